// Round 9
// baseline (236.434 us; speedup 1.0000x reference)
//
#include <hip/hip_runtime.h>
#include <math.h>

#define EPS  1e-5f
#define EPS2 1e-10f
#define MAXN (1.0f - EPS)

using short8  = __attribute__((ext_vector_type(8))) short;
using floatx4 = __attribute__((ext_vector_type(4))) float;
using float2v = __attribute__((ext_vector_type(2))) float;

template <int CTRL>
static __device__ __forceinline__ float qperm(float x) {
  return __int_as_float(__builtin_amdgcn_update_dpp(
      __float_as_int(x), __float_as_int(x), CTRL, 0xF, 0xF, false));
}
#define QP_XOR1    0xB1
#define QP_XOR2    0x4E
#define QP_HALFMIR 0x141

#if __has_builtin(__builtin_elementwise_fma)
static __device__ __forceinline__ float2v fma2(float2v a, float2v b, float2v c) {
  return __builtin_elementwise_fma(a, b, c);
}
#else
static __device__ __forceinline__ float2v fma2(float2v a, float2v b, float2v c) {
  float2v r; r.x = fmaf(a.x, b.x, c.x); r.y = fmaf(a.y, b.y, c.y); return r;
}
#endif

static __device__ __forceinline__ int pack_hi2(float a, float b) {
  return (int)((__float_as_uint(a) >> 16) | (__float_as_uint(b) & 0xFFFF0000u));
}
static __device__ __forceinline__ float hi_of(float a) {
  return __uint_as_float(__float_as_uint(a) & 0xFFFF0000u);
}

static __device__ __forceinline__ float logmap_f(float ss) {
  const float r = sqrtf(fmaxf(ss, EPS2));
  float at;
  if (r >= MAXN) {
    at = 0.5f * logf((r * (2.0f - EPS) + EPS) / (EPS * (1.0f + r)));
  } else {
    at = 0.5f * logf((1.0f + r) / (1.0f - r));
  }
  return (1.0f + EPS) * at / r;
}

// ---------- K0: pre-split W matrices to packed bf16 hi/lo ----------
__global__ __launch_bounds__(256) void k_splitW(
    const float* __restrict__ W0, const float* __restrict__ W1, const float* __restrict__ W2,
    int* __restrict__ h0, int* __restrict__ l0,
    int* __restrict__ h1, int* __restrict__ l1,
    int* __restrict__ h2, int* __restrict__ l2) {
  const int row = blockIdx.x, z = blockIdx.y, t = threadIdx.x;
  const float* W = (z == 0) ? W0 : ((z == 1) ? W1 : W2);
  int* H = (z == 0) ? h0 : ((z == 1) ? h1 : h2);
  int* L = (z == 0) ? l0 : ((z == 1) ? l1 : l2);
  const float2 w = *(const float2*)&W[(size_t)row * 512 + 2 * t];
  H[(size_t)row * 256 + t] = pack_hi2(w.x, w.y);
  L[(size_t)row * 256 + t] = pack_hi2(w.x - hi_of(w.x), w.y - hi_of(w.y));
}

// ---------- K1: pre-split A (activations) + per-row logmap factor ----------
// Removes the 8x-redundant A pack + ssq from k_gemm (each N-tile re-did it).
__global__ __launch_bounds__(256) void k_splitA(
    const float* __restrict__ A0, const float* __restrict__ A1, const float* __restrict__ A2,
    int* __restrict__ h0, int* __restrict__ l0,
    int* __restrict__ h1, int* __restrict__ l1,
    int* __restrict__ h2, int* __restrict__ l2,
    float* __restrict__ fA) {
  const int row = blockIdx.x, z = blockIdx.y, t = threadIdx.x;
  const float* A = (z == 0) ? A0 : ((z == 1) ? A1 : A2);
  int* H = (z == 0) ? h0 : ((z == 1) ? h1 : h2);
  int* L = (z == 0) ? l0 : ((z == 1) ? l1 : l2);
  const float2 a = *(const float2*)&A[(size_t)row * 512 + 2 * t];
  H[(size_t)row * 256 + t] = pack_hi2(a.x, a.y);
  L[(size_t)row * 256 + t] = pack_hi2(a.x - hi_of(a.x), a.y - hi_of(a.y));
  float p = a.x * a.x + a.y * a.y;
#pragma unroll
  for (int m = 32; m; m >>= 1) p += __shfl_xor(p, m, 64);
  __shared__ float red[4];
  const int lane = t & 63, w = t >> 6;
  if (lane == 0) red[w] = p;
  __syncthreads();
  if (t == 0) fA[(size_t)z * 2048 + row] = logmap_f(red[0] + red[1] + red[2] + red[3]);
}

// ---------- K2: C = f[row]*(A @ W^T), both operands pre-packed ----------
__global__ __launch_bounds__(256) void k_gemm_mfma(
    const int* __restrict__ Ah0, const int* __restrict__ Al0,
    const int* __restrict__ Ah1, const int* __restrict__ Al1,
    const int* __restrict__ Ah2, const int* __restrict__ Al2,
    const int* __restrict__ Wh0, const int* __restrict__ Wl0,
    const int* __restrict__ Wh1, const int* __restrict__ Wl1,
    const int* __restrict__ Wh2, const int* __restrict__ Wl2,
    const float* __restrict__ fA,
    float* __restrict__ Cbase) {
  const int z = blockIdx.z;
  const int* Ah = (z == 0) ? Ah0 : ((z == 1) ? Ah1 : Ah2);
  const int* Al = (z == 0) ? Al0 : ((z == 1) ? Al1 : Al2);
  const int* Wh = (z == 0) ? Wh0 : ((z == 1) ? Wh1 : Wh2);
  const int* Wl = (z == 0) ? Wl0 : ((z == 1) ? Wl1 : Wl2);
  float* C = Cbase + (size_t)z * (2048 * 512);
  __shared__ int Ahi[64][36], Alo[64][36], Whi[64][36], Wlo[64][36];
  __shared__ float f_lds[64];
  const int t = threadIdx.x;
  const int n0 = blockIdx.x * 64;
  const int m0 = blockIdx.y * 64;
  const int row = t >> 2, ci = (t & 3) * 8;
  const int w = t >> 6, lane = t & 63;
  const int quad = lane >> 4, l16 = lane & 15;
  const int mw = (w & 1) * 32, nw = (w >> 1) * 32;
  if (t < 64) f_lds[t] = fA[(size_t)z * 2048 + n0 + t];
  floatx4 acc[2][2];
#pragma unroll
  for (int i = 0; i < 2; ++i)
#pragma unroll
    for (int j = 0; j < 2; ++j) acc[i][j] = (floatx4){0.f, 0.f, 0.f, 0.f};

  for (int k0 = 0; k0 < 512; k0 += 64) {
    const size_t abase = (size_t)(n0 + row) * 256 + (k0 >> 1) + ci;
    const size_t wbase = (size_t)(m0 + row) * 256 + (k0 >> 1) + ci;
    const int4 ah0 = *(const int4*)&Ah[abase];
    const int4 ah1 = *(const int4*)&Ah[abase + 4];
    const int4 al0 = *(const int4*)&Al[abase];
    const int4 al1 = *(const int4*)&Al[abase + 4];
    const int4 wh0 = *(const int4*)&Wh[wbase];
    const int4 wh1 = *(const int4*)&Wh[wbase + 4];
    const int4 wl0 = *(const int4*)&Wl[wbase];
    const int4 wl1 = *(const int4*)&Wl[wbase + 4];
    __syncthreads();
    *(int4*)&Ahi[row][ci]     = ah0;
    *(int4*)&Ahi[row][ci + 4] = ah1;
    *(int4*)&Alo[row][ci]     = al0;
    *(int4*)&Alo[row][ci + 4] = al1;
    *(int4*)&Whi[row][ci]     = wh0;
    *(int4*)&Whi[row][ci + 4] = wh1;
    *(int4*)&Wlo[row][ci]     = wl0;
    *(int4*)&Wlo[row][ci + 4] = wl1;
    __syncthreads();
#pragma unroll
    for (int kk = 0; kk < 64; kk += 32) {
      short8 ah[2], al[2], bh[2], bl[2];
#pragma unroll
      for (int i = 0; i < 2; ++i) {
        ah[i] = *(const short8*)&((const short*)Ahi[mw + i * 16 + l16])[kk + quad * 8];
        al[i] = *(const short8*)&((const short*)Alo[mw + i * 16 + l16])[kk + quad * 8];
        bh[i] = *(const short8*)&((const short*)Whi[nw + i * 16 + l16])[kk + quad * 8];
        bl[i] = *(const short8*)&((const short*)Wlo[nw + i * 16 + l16])[kk + quad * 8];
      }
#pragma unroll
      for (int i = 0; i < 2; ++i)
#pragma unroll
        for (int j = 0; j < 2; ++j) {
          acc[i][j] = __builtin_amdgcn_mfma_f32_16x16x32_bf16(ah[i], bh[j], acc[i][j], 0, 0, 0);
          acc[i][j] = __builtin_amdgcn_mfma_f32_16x16x32_bf16(ah[i], bl[j], acc[i][j], 0, 0, 0);
          acc[i][j] = __builtin_amdgcn_mfma_f32_16x16x32_bf16(al[i], bh[j], acc[i][j], 0, 0, 0);
        }
    }
  }
  __syncthreads();
#pragma unroll
  for (int i = 0; i < 2; ++i) {
    const int lrow_base = mw + i * 16 + quad * 4;
#pragma unroll
    for (int r = 0; r < 4; ++r) {
      const float fv = f_lds[lrow_base + r];
#pragma unroll
      for (int j = 0; j < 2; ++j)
        C[(size_t)(n0 + lrow_base + r) * 512 + m0 + nw + j * 16 + l16] = fv * acc[i][j][r];
    }
  }
}

// ---------- K3: expmap0 + mobius-add bias; Q/K emitted PRE-PACKED bf16 hi/lo ----------
__global__ __launch_bounds__(256) void k_post(const float* __restrict__ tin,
                                              const float* __restrict__ b0,
                                              const float* __restrict__ b1,
                                              const float* __restrict__ b2,
                                              float* __restrict__ o0, float* __restrict__ o1,
                                              float* __restrict__ o2,
                                              float* __restrict__ nrm0, float* __restrict__ nrm1,
                                              float* __restrict__ nrm2,
                                              float* __restrict__ rowsum_init,
                                              int* __restrict__ qhi, int* __restrict__ qlo,
                                              int* __restrict__ khi, int* __restrict__ klo,
                                              int final_mode) {
  const int nrow = blockIdx.x, z = blockIdx.y, t = threadIdx.x;
  const float* tv = tin + ((size_t)z * 2048 + nrow) * 512;
  const float* bias = (z == 0) ? b0 : ((z == 1) ? b1 : b2);
  const int e0 = 2 * t;
  const float2 tp = *(const float2*)&tv[e0];
  const float2 bp = *(const float2*)&bias[e0];
  float p_tt = tp.x * tp.x + tp.y * tp.y;
  float p_tb = tp.x * bp.x + tp.y * bp.y;
  float p_bb = bp.x * bp.x + bp.y * bp.y;
#pragma unroll
  for (int m = 32; m; m >>= 1) {
    p_tt += __shfl_xor(p_tt, m, 64);
    p_tb += __shfl_xor(p_tb, m, 64);
    p_bb += __shfl_xor(p_bb, m, 64);
  }
  __shared__ float red[4][3];
  const int lane = t & 63, w = t >> 6;
  if (lane == 0) { red[w][0] = p_tt; red[w][1] = p_tb; red[w][2] = p_bb; }
  __syncthreads();
  const float s_tt = red[0][0] + red[1][0] + red[2][0] + red[3][0];
  const float s_tb = red[0][1] + red[1][1] + red[2][1] + red[3][1];
  const float s_bb = red[0][2] + red[1][2] + red[2][2] + red[3][2];
  const float tn = sqrtf(fmaxf(s_tt, EPS2));
  const float th = tanhf(tn / (1.0f + EPS));
  const float g = th / tn;
  const float rnorm = th * (sqrtf(s_tt) / tn);
  const float sr = (rnorm >= MAXN) ? (MAXN / (rnorm + EPS)) : 1.0f;
  const float gr = g * sr;
  const float rn = (rnorm * sr) * (rnorm * sr);
  const float bnorm = sqrtf(fmaxf(s_bb, EPS2));
  const float sb = (bnorm >= MAXN) ? (MAXN / (bnorm + EPS)) : 1.0f;
  const float xy = gr * sb * s_tb;
  const float yn = (sb * sb) * s_bb;
  const float Af = 1.0f + 2.0f * xy + yn;
  const float Cf = 1.0f - rn;
  const float den = 1.0f + 2.0f * xy + rn * yn + EPS;
  const float id = 1.0f / den;
  const float on_raw = (Af * Af * rn + 2.0f * Af * Cf * xy + Cf * Cf * yn) * (id * id);
  const float no = sqrtf(fmaxf(on_raw, EPS2));
  const float so = (no >= MAXN) ? (MAXN / (no + EPS)) : 1.0f;
  const float ms = id * so;
  const float ca = gr * Af * ms;
  const float cb = sb * Cf * ms;
  const float v0 = ca * tp.x + cb * bp.x;
  const float v1 = ca * tp.y + cb * bp.y;
  if (final_mode) {
    float2 o; o.x = v0; o.y = v1;
    *(float2*)&o0[(size_t)nrow * 512 + e0] = o;
    return;
  }
  float hp = v0 * v0 + v1 * v1;
#pragma unroll
  for (int m = 16; m; m >>= 1) hp += __shfl_xor(hp, m, 64);
  const float hnr = sqrtf(fmaxf(hp, EPS2));
  float sh = 1.0f;
  if (z != 2) sh = (hnr >= MAXN) ? (MAXN / (hnr + EPS)) : 1.0f;
  float* nz = (z == 0) ? nrm0 : ((z == 1) ? nrm1 : nrm2);
  const int b = nrow >> 9, s = nrow & 511, h = e0 >> 6, d = e0 & 63;
  const float ox = v0 * sh, oy = v1 * sh;
  if (z == 2) {
    float2 o; o.x = ox; o.y = oy;
    *(float2*)&o2[(((size_t)(b * 8 + h) * 512 + s) * 64 + d)] = o;
  } else {
    int* Hp = (z == 0) ? qhi : khi;
    int* Lp = (z == 0) ? qlo : klo;
    const size_t pidx = ((size_t)(b * 8 + h) * 512 + s) * 32 + (d >> 1);
    Hp[pidx] = pack_hi2(ox, oy);
    Lp[pidx] = pack_hi2(ox - hi_of(ox), oy - hi_of(oy));
  }
  if ((t & 31) == 0) nz[(size_t)(b * 8 + h) * 512 + s] = hp * sh * sh;
  if (z == 0 && t < 8) rowsum_init[((size_t)(nrow >> 9) * 8 + t) * 512 + (nrow & 511)] = 0.0f;
}

// ---------- K4: QK^T from pre-packed Q/K ----------
__global__ __launch_bounds__(256) void k_logits(const int* __restrict__ QhiG,
                                                const int* __restrict__ QloG,
                                                const int* __restrict__ KhiG,
                                                const int* __restrict__ KloG,
                                                const float* __restrict__ qn,
                                                const float* __restrict__ kn,
                                                float* __restrict__ attn,
                                                float* __restrict__ rowsum) {
  const int bh = blockIdx.z;
  const int i0 = blockIdx.x * 64;
  const int j0 = blockIdx.y * 64;
  __shared__ int Qhi[64][36], Qlo[64][36], Khi[64][36], Klo[64][36];
  const int t = threadIdx.x;
  const int row = t >> 2, ci = (t & 3) * 8;
  const int w = t >> 6, lane = t & 63;
  const int quad = lane >> 4, l16 = lane & 15;
  const int mw = (w & 1) * 32, nw = (w >> 1) * 32;
  const size_t qbase = ((size_t)bh * 512 + i0 + row) * 32 + ci;
  const size_t kbase = ((size_t)bh * 512 + j0 + row) * 32 + ci;
  const int4 qh0 = *(const int4*)&QhiG[qbase];
  const int4 qh1 = *(const int4*)&QhiG[qbase + 4];
  const int4 ql0 = *(const int4*)&QloG[qbase];
  const int4 ql1 = *(const int4*)&QloG[qbase + 4];
  const int4 kh0 = *(const int4*)&KhiG[kbase];
  const int4 kh1 = *(const int4*)&KhiG[kbase + 4];
  const int4 kl0 = *(const int4*)&KloG[kbase];
  const int4 kl1 = *(const int4*)&KloG[kbase + 4];
  *(int4*)&Qhi[row][ci]     = qh0;
  *(int4*)&Qhi[row][ci + 4] = qh1;
  *(int4*)&Qlo[row][ci]     = ql0;
  *(int4*)&Qlo[row][ci + 4] = ql1;
  *(int4*)&Khi[row][ci]     = kh0;
  *(int4*)&Khi[row][ci + 4] = kh1;
  *(int4*)&Klo[row][ci]     = kl0;
  *(int4*)&Klo[row][ci + 4] = kl1;
  __syncthreads();
  floatx4 acc[2][2];
#pragma unroll
  for (int i = 0; i < 2; ++i)
#pragma unroll
    for (int j = 0; j < 2; ++j) acc[i][j] = (floatx4){0.f, 0.f, 0.f, 0.f};
#pragma unroll
  for (int kk = 0; kk < 64; kk += 32) {
    short8 ah[2], al[2], bhv[2], blv[2];
#pragma unroll
    for (int i = 0; i < 2; ++i) {
      ah[i]  = *(const short8*)&((const short*)Qhi[mw + i * 16 + l16])[kk + quad * 8];
      al[i]  = *(const short8*)&((const short*)Qlo[mw + i * 16 + l16])[kk + quad * 8];
      bhv[i] = *(const short8*)&((const short*)Khi[nw + i * 16 + l16])[kk + quad * 8];
      blv[i] = *(const short8*)&((const short*)Klo[nw + i * 16 + l16])[kk + quad * 8];
    }
#pragma unroll
    for (int i = 0; i < 2; ++i)
#pragma unroll
      for (int j = 0; j < 2; ++j) {
        acc[i][j] = __builtin_amdgcn_mfma_f32_16x16x32_bf16(ah[i], bhv[j], acc[i][j], 0, 0, 0);
        acc[i][j] = __builtin_amdgcn_mfma_f32_16x16x32_bf16(ah[i], blv[j], acc[i][j], 0, 0, 0);
        acc[i][j] = __builtin_amdgcn_mfma_f32_16x16x32_bf16(al[i], bhv[j], acc[i][j], 0, 0, 0);
      }
  }
#pragma unroll
  for (int i = 0; i < 2; ++i) {
    float rs_acc[4] = {0.f, 0.f, 0.f, 0.f};
#pragma unroll
    for (int r = 0; r < 4; ++r) {
      const int grow = i0 + mw + i * 16 + quad * 4 + r;
      const float qni = qn[(size_t)bh * 512 + grow];
      const float rq = 1.0f - qni;
#pragma unroll
      for (int j = 0; j < 2; ++j) {
        const int gcol = j0 + nw + j * 16 + l16;
        const float knj = kn[(size_t)bh * 512 + gcol];
        const float num = fmaxf(qni + knj - 2.0f * acc[i][j][r], 0.0f);
        const float den = fmaxf(rq * (1.0f - knj), EPS);
        const float wv = fmaf(2.0f * num, __builtin_amdgcn_rcpf(den), EPS);
        const float s_ = 1.0f + wv + sqrtf(wv * (wv + 2.0f));
        const float rr = __builtin_amdgcn_rcpf(s_);
        rs_acc[r] += rr;
        attn[((size_t)bh * 512 + grow) * 512 + gcol] = rr;
      }
    }
#pragma unroll
    for (int r = 0; r < 4; ++r) {
      float v = rs_acc[r];
      v += __shfl_xor(v, 1, 64); v += __shfl_xor(v, 2, 64);
      v += __shfl_xor(v, 4, 64); v += __shfl_xor(v, 8, 64);
      if (l16 == 0)
        atomicAdd(&rowsum[(size_t)bh * 512 + i0 + mw + i * 16 + quad * 4 + r], v);
    }
  }
}

// ---------- K6 v13: mobius scan (verified best) ----------
__global__ __launch_bounds__(256) void k_scan(const float* __restrict__ V,
                                              const float* __restrict__ vn,
                                              const float* __restrict__ rw,
                                              const float* __restrict__ rowsum,
                                              float* __restrict__ att) {
  __shared__ __align__(16) float v_lds[64 * 64];
  __shared__ __align__(16) float swyn_lds[64 * 66];
  const int blk = blockIdx.x;
  const int bh = blk >> 4;
  const int i0 = (blk & 15) * 32;
  const int t = threadIdx.x;
  const int lane = t & 63, w = t >> 6;
  const int row_blk = w * 8 + (lane >> 3);
  const int sub = lane & 7;
  const int d0 = sub * 8;
  const float* Vb = V + (size_t)bh * 512 * 64;
  const float* vnb = vn + (size_t)bh * 512;
  const float* arow = rw + ((size_t)bh * 512 + i0 + row_blk) * 512;
  const float inv_s = __builtin_amdgcn_rcpf(rowsum[(size_t)bh * 512 + i0 + row_blk]);

  float2v wsv[4];
#pragma unroll
  for (int k = 0; k < 4; ++k) wsv[k] = (float2v){0.f, 0.f};
  float xn = 0.0f;

  for (int jc = 0; jc < 512; jc += 64) {
#pragma unroll
    for (int it = 0; it < 4; ++it) {
      const int idx4 = it * 256 + t;
      *(float4*)&v_lds[idx4 * 4] = *(const float4*)&Vb[(size_t)jc * 64 + idx4 * 4];
    }
    const float4 a0 = *(const float4*)&arow[jc + sub * 8];
    const float4 a1 = *(const float4*)&arow[jc + sub * 8 + 4];
    const float4 n0 = *(const float4*)&vnb[jc + sub * 8];
    const float4 n1 = *(const float4*)&vnb[jc + sub * 8 + 4];
    const float wq[8] = {a0.x, a0.y, a0.z, a0.w, a1.x, a1.y, a1.z, a1.w};
    const float nq[8] = {n0.x, n0.y, n0.z, n0.w, n1.x, n1.y, n1.z, n1.w};
#pragma unroll
    for (int e = 0; e < 8; ++e) {
      const float wgt = wq[e] * inv_s;
      float2 p; p.x = wgt; p.y = (wgt * wgt) * nq[e];
      *(float2*)&swyn_lds[(sub * 8 + e) * 66 + row_blk * 2] = p;
    }
    __syncthreads();

    float4 pv0 = *(const float4*)&v_lds[d0];
    float4 pv1 = *(const float4*)&v_lds[d0 + 4];
    float2 psy = *(const float2*)&swyn_lds[row_blk * 2];
#pragma unroll
    for (int j = 0; j < 64; ++j) {
      const float4 v0 = pv0;
      const float4 v1 = pv1;
      const float2 sy2 = psy;
      if (j < 63) {
        pv0 = *(const float4*)&v_lds[(j + 1) * 64 + d0];
        pv1 = *(const float4*)&v_lds[(j + 1) * 64 + d0 + 4];
        psy = *(const float2*)&swyn_lds[(j + 1) * 66 + row_blk * 2];
      }
      const float2v vv0 = {v0.x, v0.y}, vv1 = {v0.z, v0.w};
      const float2v vv2 = {v1.x, v1.y}, vv3 = {v1.z, v1.w};
      const float sw = sy2.x, yn = sy2.y;
      const float xnyn1 = fmaf(xn, yn, 1.0f + EPS);
      const float sxy   = xn + yn;
      const float ynp1  = 1.0f + yn;
      const float Cfsw  = (1.0f - xn) * sw;
      float2v da = wsv[0] * vv0;
      da = fma2(wsv[1], vv1, da);
      float2v db = wsv[2] * vv2;
      db = fma2(wsv[3], vv3, db);
      const float2v sv = da + db;
      float d = sv.x + sv.y;
      d += qperm<QP_XOR1>(d);
      d += qperm<QP_XOR2>(d);
      d += qperm<QP_HALFMIR>(d);
      const float xy  = sw * d;
      const float den = fmaf(2.0f, xy, xnyn1);
      const float s2  = fmaf(2.0f, xy, sxy);
      const float Af  = fmaf(2.0f, xy, ynp1);
      const float id  = __builtin_amdgcn_rcpf(den);
      const float dn  = den - EPS;
      const float am  = Af * id;
      const float cm  = Cfsw * id;
      xn = (s2 * id) * (dn * id);
      const float2v amv = {am, am};
      const float2v cmv = {cm, cm};
      wsv[0] = fma2(amv, wsv[0], cmv * vv0);
      wsv[1] = fma2(amv, wsv[1], cmv * vv1);
      wsv[2] = fma2(amv, wsv[2], cmv * vv2);
      wsv[3] = fma2(amv, wsv[3], cmv * vv3);
    }
    __syncthreads();
  }
  const int b = bh >> 3, h = bh & 7;
  float* o = att + (((size_t)b * 512 + i0 + row_blk) * 512 + h * 64 + d0);
  float4 s0; s0.x = wsv[0].x; s0.y = wsv[0].y; s0.z = wsv[1].x; s0.w = wsv[1].y;
  float4 s1; s1.x = wsv[2].x; s1.y = wsv[2].y; s1.z = wsv[3].x; s1.w = wsv[3].y;
  *(float4*)&o[0] = s0;
  *(float4*)&o[4] = s1;
}

extern "C" void kernel_launch(void* const* d_in, const int* in_sizes, int n_in,
                              void* d_out, int out_size, void* d_ws, size_t ws_size,
                              hipStream_t stream) {
  const float* query = (const float*)d_in[0];
  const float* key_  = (const float*)d_in[1];
  const float* value = (const float*)d_in[2];
  const float* Wq = (const float*)d_in[3];
  const float* bq = (const float*)d_in[4];
  const float* Wk = (const float*)d_in[5];
  const float* bk = (const float*)d_in[6];
  const float* Wv = (const float*)d_in[7];
  const float* bv = (const float*)d_in[8];
  const float* Wo = (const float*)d_in[9];
  const float* bo = (const float*)d_in[10];
  float* ws = (float*)d_ws;
  const size_t M = 1u << 20;            // 1M floats
  // packed Q/K in [0, 2M)
  int* qhi = (int*)ws;
  int* qlo = (int*)ws + 524288;
  int* khi = (int*)ws + 1048576;
  int* klo = (int*)ws + 1572864;
  float* Vb     = ws + 2 * M;           // [32,512,64]
  float* qn     = ws + 3 * M;           // [32,512]
  float* kn     = qn + 16384;
  float* vn     = kn + 16384;
  float* rowsum = vn + 16384;           // ends at 3M + 65536
  // W splits
  int* wsl = (int*)(ws + 3 * M + 65536);
  int* whq = wsl,          * wlq = wsl + 131072;
  int* whk = wsl + 262144, * wlk = wsl + 393216;
  int* whv = wsl + 524288, * wlv = wsl + 655360;   // ends 3M + 65536 + 786432
  float* fqkv = ws + 3 * M + 65536 + 786432;       // 3*2048 floats
  float* fatt = fqkv + 3 * 2048;                   // 2048 floats; ends < 4M
  float* rw     = ws + 4 * M;           // [32,512,512], written by k_logits (step 6)
  // packed A (q/k/v): inside rw region — dead before k_logits writes rw
  int* aqh = (int*)(ws + 4 * M);                   // per z: hi 512K + lo 512K ints
  int* aql = aqh + 524288;
  int* akh = aqh + 1048576, * akl = aqh + 1572864;
  int* avh = aqh + 2097152, * avl = aqh + 2621440; // ends 4M + 3M ints
  // packed att: also in rw region [7M, 8M) — written after k_scan (rw dead)
  int* athi = (int*)(ws + 7 * M);
  int* atlo = athi + 524288;
  float* t3     = ws + 12 * M;          // 3x [2048,512]
  int* who  = (int*)(ws + 12 * M);      // Wo split reuses t3 (dead after k_post)
  int* wlo_ = (int*)(ws + 12 * M) + 131072;
  float* att    = ws + 15 * M;
  float* to_    = ws + 16 * M;

  k_splitW<<<dim3(512, 3), 256, 0, stream>>>(Wq, Wk, Wv, whq, wlq, whk, wlk, whv, wlv);
  k_splitA<<<dim3(2048, 3), 256, 0, stream>>>(query, key_, value,
                                              aqh, aql, akh, akl, avh, avl, fqkv);
  k_gemm_mfma<<<dim3(32, 8, 3), 256, 0, stream>>>(aqh, aql, akh, akl, avh, avl,
                                                  whq, wlq, whk, wlk, whv, wlv,
                                                  fqkv, t3);
  k_post<<<dim3(2048, 3), 256, 0, stream>>>(t3, bq, bk, bv, nullptr, nullptr, Vb,
                                            qn, kn, vn, rowsum, qhi, qlo, khi, klo, 0);
  k_splitW<<<dim3(512, 1), 256, 0, stream>>>(Wo, Wo, Wo, who, wlo_, who, wlo_, who, wlo_);
  k_logits<<<dim3(8, 8, 32), 256, 0, stream>>>(qhi, qlo, khi, klo, qn, kn, rw, rowsum);
  k_scan<<<512, 256, 0, stream>>>(Vb, vn, rw, rowsum, att);
  k_splitA<<<dim3(2048, 1), 256, 0, stream>>>(att, att, att,
                                              athi, atlo, athi, atlo, athi, atlo, fatt);
  k_gemm_mfma<<<dim3(32, 8, 1), 256, 0, stream>>>(athi, atlo, athi, atlo, athi, atlo,
                                                  who, wlo_, who, wlo_, who, wlo_,
                                                  fatt, to_);
  k_post<<<dim3(2048, 1), 256, 0, stream>>>(to_, bo, bo, bo, (float*)d_out,
                                            nullptr, nullptr, nullptr, nullptr, nullptr,
                                            nullptr, nullptr, nullptr, nullptr, nullptr, 1);
}

// Round 10
// 231.908 us; speedup vs baseline: 1.0195x; 1.0195x over previous
//
#include <hip/hip_runtime.h>
#include <math.h>

#define EPS  1e-5f
#define EPS2 1e-10f
#define MAXN (1.0f - EPS)

using short8  = __attribute__((ext_vector_type(8))) short;
using floatx4 = __attribute__((ext_vector_type(4))) float;
using float2v = __attribute__((ext_vector_type(2))) float;

template <int CTRL>
static __device__ __forceinline__ float qperm(float x) {
  return __int_as_float(__builtin_amdgcn_update_dpp(
      __float_as_int(x), __float_as_int(x), CTRL, 0xF, 0xF, false));
}
#define QP_XOR1    0xB1
#define QP_XOR2    0x4E
#define QP_HALFMIR 0x141

#if __has_builtin(__builtin_elementwise_fma)
static __device__ __forceinline__ float2v fma2(float2v a, float2v b, float2v c) {
  return __builtin_elementwise_fma(a, b, c);
}
#else
static __device__ __forceinline__ float2v fma2(float2v a, float2v b, float2v c) {
  float2v r; r.x = fmaf(a.x, b.x, c.x); r.y = fmaf(a.y, b.y, c.y); return r;
}
#endif

static __device__ __forceinline__ int pack_hi2(float a, float b) {
  return (int)((__float_as_uint(a) >> 16) | (__float_as_uint(b) & 0xFFFF0000u));
}
static __device__ __forceinline__ float hi_of(float a) {
  return __uint_as_float(__float_as_uint(a) & 0xFFFF0000u);
}

static __device__ __forceinline__ float logmap_f(float ss) {
  const float r = sqrtf(fmaxf(ss, EPS2));
  float at;
  if (r >= MAXN) {
    at = 0.5f * logf((r * (2.0f - EPS) + EPS) / (EPS * (1.0f + r)));
  } else {
    at = 0.5f * logf((1.0f + r) / (1.0f - r));
  }
  return (1.0f + EPS) * at / r;
}

// ---------- K1: pre-split W matrices to packed bf16 hi/lo ----------
__global__ __launch_bounds__(256) void k_splitW(
    const float* __restrict__ W0, const float* __restrict__ W1, const float* __restrict__ W2,
    int* __restrict__ h0, int* __restrict__ l0,
    int* __restrict__ h1, int* __restrict__ l1,
    int* __restrict__ h2, int* __restrict__ l2) {
  const int row = blockIdx.x, z = blockIdx.y, t = threadIdx.x;
  const float* W = (z == 0) ? W0 : ((z == 1) ? W1 : W2);
  int* H = (z == 0) ? h0 : ((z == 1) ? h1 : h2);
  int* L = (z == 0) ? l0 : ((z == 1) ? l1 : l2);
  const float2 w = *(const float2*)&W[(size_t)row * 512 + 2 * t];
  H[(size_t)row * 256 + t] = pack_hi2(w.x, w.y);
  L[(size_t)row * 256 + t] = pack_hi2(w.x - hi_of(w.x), w.y - hi_of(w.y));
}

// ---------- K2: C = f[row]*(A @ W^T), W pre-split ----------
__global__ __launch_bounds__(256) void k_gemm_mfma(
    const float* __restrict__ A0, const float* __restrict__ A1, const float* __restrict__ A2,
    const int* __restrict__ Wh0, const int* __restrict__ Wl0,
    const int* __restrict__ Wh1, const int* __restrict__ Wl1,
    const int* __restrict__ Wh2, const int* __restrict__ Wl2,
    float* __restrict__ Cbase) {
  const int z = blockIdx.z;
  const float* A = (z == 0) ? A0 : ((z == 1) ? A1 : A2);
  const int* Wh = (z == 0) ? Wh0 : ((z == 1) ? Wh1 : Wh2);
  const int* Wl = (z == 0) ? Wl0 : ((z == 1) ? Wl1 : Wl2);
  float* C = Cbase + (size_t)z * (2048 * 512);
  __shared__ int Ahi[64][36], Alo[64][36], Whi[64][36], Wlo[64][36];
  __shared__ float f_lds[64];
  const int t = threadIdx.x;
  const int n0 = blockIdx.x * 64;
  const int m0 = blockIdx.y * 64;
  const int row = t >> 2, c0 = (t & 3) * 16, ci = (t & 3) * 8;
  const int w = t >> 6, lane = t & 63;
  const int quad = lane >> 4, l16 = lane & 15;
  const int mw = (w & 1) * 32, nw = (w >> 1) * 32;
  floatx4 acc[2][2];
#pragma unroll
  for (int i = 0; i < 2; ++i)
#pragma unroll
    for (int j = 0; j < 2; ++j) acc[i][j] = (floatx4){0.f, 0.f, 0.f, 0.f};
  float ssq = 0.0f;

  for (int k0 = 0; k0 < 512; k0 += 64) {
    float4 av[4];
#pragma unroll
    for (int i = 0; i < 4; ++i)
      av[i] = *(const float4*)&A[(size_t)(n0 + row) * 512 + k0 + c0 + 4 * i];
    const size_t wbase = (size_t)(m0 + row) * 256 + (k0 >> 1) + ci;
    const int4 wh0 = *(const int4*)&Wh[wbase];
    const int4 wh1 = *(const int4*)&Wh[wbase + 4];
    const int4 wl0 = *(const int4*)&Wl[wbase];
    const int4 wl1 = *(const int4*)&Wl[wbase + 4];
    int pAh[8], pAl[8];
#pragma unroll
    for (int i = 0; i < 4; ++i) {
      ssq = fmaf(av[i].x, av[i].x, ssq); ssq = fmaf(av[i].y, av[i].y, ssq);
      ssq = fmaf(av[i].z, av[i].z, ssq); ssq = fmaf(av[i].w, av[i].w, ssq);
      pAh[2 * i]     = pack_hi2(av[i].x, av[i].y);
      pAh[2 * i + 1] = pack_hi2(av[i].z, av[i].w);
      pAl[2 * i]     = pack_hi2(av[i].x - hi_of(av[i].x), av[i].y - hi_of(av[i].y));
      pAl[2 * i + 1] = pack_hi2(av[i].z - hi_of(av[i].z), av[i].w - hi_of(av[i].w));
    }
    __syncthreads();
    *(int4*)&Ahi[row][ci]     = *(int4*)&pAh[0];
    *(int4*)&Ahi[row][ci + 4] = *(int4*)&pAh[4];
    *(int4*)&Alo[row][ci]     = *(int4*)&pAl[0];
    *(int4*)&Alo[row][ci + 4] = *(int4*)&pAl[4];
    *(int4*)&Whi[row][ci]     = wh0;
    *(int4*)&Whi[row][ci + 4] = wh1;
    *(int4*)&Wlo[row][ci]     = wl0;
    *(int4*)&Wlo[row][ci + 4] = wl1;
    __syncthreads();
#pragma unroll
    for (int kk = 0; kk < 64; kk += 32) {
      short8 ah[2], al[2], bh[2], bl[2];
#pragma unroll
      for (int i = 0; i < 2; ++i) {
        ah[i] = *(const short8*)&((const short*)Ahi[mw + i * 16 + l16])[kk + quad * 8];
        al[i] = *(const short8*)&((const short*)Alo[mw + i * 16 + l16])[kk + quad * 8];
        bh[i] = *(const short8*)&((const short*)Whi[nw + i * 16 + l16])[kk + quad * 8];
        bl[i] = *(const short8*)&((const short*)Wlo[nw + i * 16 + l16])[kk + quad * 8];
      }
#pragma unroll
      for (int i = 0; i < 2; ++i)
#pragma unroll
        for (int j = 0; j < 2; ++j) {
          acc[i][j] = __builtin_amdgcn_mfma_f32_16x16x32_bf16(ah[i], bh[j], acc[i][j], 0, 0, 0);
          acc[i][j] = __builtin_amdgcn_mfma_f32_16x16x32_bf16(ah[i], bl[j], acc[i][j], 0, 0, 0);
          acc[i][j] = __builtin_amdgcn_mfma_f32_16x16x32_bf16(al[i], bh[j], acc[i][j], 0, 0, 0);
        }
    }
  }
  ssq += qperm<QP_XOR1>(ssq);
  ssq += qperm<QP_XOR2>(ssq);
  if ((t & 3) == 0) f_lds[row] = logmap_f(ssq);
  __syncthreads();
#pragma unroll
  for (int i = 0; i < 2; ++i) {
    const int lrow_base = mw + i * 16 + quad * 4;
#pragma unroll
    for (int r = 0; r < 4; ++r) {
      const float fv = f_lds[lrow_base + r];
#pragma unroll
      for (int j = 0; j < 2; ++j)
        C[(size_t)(n0 + lrow_base + r) * 512 + m0 + nw + j * 16 + l16] = fv * acc[i][j][r];
    }
  }
}

// ---------- K3: expmap0 + mobius-add bias; Q/K emitted PRE-PACKED bf16 hi/lo ----------
__global__ __launch_bounds__(256) void k_post(const float* __restrict__ tin,
                                              const float* __restrict__ b0,
                                              const float* __restrict__ b1,
                                              const float* __restrict__ b2,
                                              float* __restrict__ o0, float* __restrict__ o1,
                                              float* __restrict__ o2,
                                              float* __restrict__ nrm0, float* __restrict__ nrm1,
                                              float* __restrict__ nrm2,
                                              float* __restrict__ rowsum_init,
                                              int* __restrict__ qhi, int* __restrict__ qlo,
                                              int* __restrict__ khi, int* __restrict__ klo,
                                              int final_mode) {
  const int nrow = blockIdx.x, z = blockIdx.y, t = threadIdx.x;
  const float* tv = tin + ((size_t)z * 2048 + nrow) * 512;
  const float* bias = (z == 0) ? b0 : ((z == 1) ? b1 : b2);
  const int e0 = 2 * t;
  const float2 tp = *(const float2*)&tv[e0];
  const float2 bp = *(const float2*)&bias[e0];
  float p_tt = tp.x * tp.x + tp.y * tp.y;
  float p_tb = tp.x * bp.x + tp.y * bp.y;
  float p_bb = bp.x * bp.x + bp.y * bp.y;
#pragma unroll
  for (int m = 32; m; m >>= 1) {
    p_tt += __shfl_xor(p_tt, m, 64);
    p_tb += __shfl_xor(p_tb, m, 64);
    p_bb += __shfl_xor(p_bb, m, 64);
  }
  __shared__ float red[4][3];
  const int lane = t & 63, w = t >> 6;
  if (lane == 0) { red[w][0] = p_tt; red[w][1] = p_tb; red[w][2] = p_bb; }
  __syncthreads();
  const float s_tt = red[0][0] + red[1][0] + red[2][0] + red[3][0];
  const float s_tb = red[0][1] + red[1][1] + red[2][1] + red[3][1];
  const float s_bb = red[0][2] + red[1][2] + red[2][2] + red[3][2];
  const float tn = sqrtf(fmaxf(s_tt, EPS2));
  const float th = tanhf(tn / (1.0f + EPS));
  const float g = th / tn;
  const float rnorm = th * (sqrtf(s_tt) / tn);
  const float sr = (rnorm >= MAXN) ? (MAXN / (rnorm + EPS)) : 1.0f;
  const float gr = g * sr;
  const float rn = (rnorm * sr) * (rnorm * sr);
  const float bnorm = sqrtf(fmaxf(s_bb, EPS2));
  const float sb = (bnorm >= MAXN) ? (MAXN / (bnorm + EPS)) : 1.0f;
  const float xy = gr * sb * s_tb;
  const float yn = (sb * sb) * s_bb;
  const float Af = 1.0f + 2.0f * xy + yn;
  const float Cf = 1.0f - rn;
  const float den = 1.0f + 2.0f * xy + rn * yn + EPS;
  const float id = 1.0f / den;
  const float on_raw = (Af * Af * rn + 2.0f * Af * Cf * xy + Cf * Cf * yn) * (id * id);
  const float no = sqrtf(fmaxf(on_raw, EPS2));
  const float so = (no >= MAXN) ? (MAXN / (no + EPS)) : 1.0f;
  const float ms = id * so;
  const float ca = gr * Af * ms;
  const float cb = sb * Cf * ms;
  const float v0 = ca * tp.x + cb * bp.x;
  const float v1 = ca * tp.y + cb * bp.y;
  if (final_mode) {
    float2 o; o.x = v0; o.y = v1;
    *(float2*)&o0[(size_t)nrow * 512 + e0] = o;
    return;
  }
  float hp = v0 * v0 + v1 * v1;
#pragma unroll
  for (int m = 16; m; m >>= 1) hp += __shfl_xor(hp, m, 64);
  const float hnr = sqrtf(fmaxf(hp, EPS2));
  float sh = 1.0f;
  if (z != 2) sh = (hnr >= MAXN) ? (MAXN / (hnr + EPS)) : 1.0f;
  float* nz = (z == 0) ? nrm0 : ((z == 1) ? nrm1 : nrm2);
  const int b = nrow >> 9, s = nrow & 511, h = e0 >> 6, d = e0 & 63;
  const float ox = v0 * sh, oy = v1 * sh;
  if (z == 2) {
    float2 o; o.x = ox; o.y = oy;
    *(float2*)&o2[(((size_t)(b * 8 + h) * 512 + s) * 64 + d)] = o;
  } else {
    int* Hp = (z == 0) ? qhi : khi;
    int* Lp = (z == 0) ? qlo : klo;
    const size_t pidx = ((size_t)(b * 8 + h) * 512 + s) * 32 + (d >> 1);
    Hp[pidx] = pack_hi2(ox, oy);
    Lp[pidx] = pack_hi2(ox - hi_of(ox), oy - hi_of(oy));
  }
  if ((t & 31) == 0) nz[(size_t)(b * 8 + h) * 512 + s] = hp * sh * sh;
  if (z == 0 && t < 8) rowsum_init[((size_t)(nrow >> 9) * 8 + t) * 512 + (nrow & 511)] = 0.0f;
}

// ---------- K4 v2: QK^T from pre-packed Q/K; Q staged ONCE, 4 K-tiles per block ----------
// Round-9 diagnosis: non-scan time is launch/staging-overhead bound. Old k_logits:
// 2048 blocks, each re-staging a Q-tile 8 siblings also stage (8x redundant) + 16
// rowsum atomics/row. Now: 512 blocks loop 4 K-tiles; Q staged once; qn hoisted;
// rowsum accumulated in regs, 4x fewer atomics. rr/attn math bit-identical.
__global__ __launch_bounds__(256) void k_logits(const int* __restrict__ QhiG,
                                                const int* __restrict__ QloG,
                                                const int* __restrict__ KhiG,
                                                const int* __restrict__ KloG,
                                                const float* __restrict__ qn,
                                                const float* __restrict__ kn,
                                                float* __restrict__ attn,
                                                float* __restrict__ rowsum) {
  const int bh = blockIdx.z;
  const int i0 = blockIdx.x * 64;
  const int jh = blockIdx.y;                 // j-half: K tiles jh*256 + {0,64,128,192}
  __shared__ int Qhi[64][36], Qlo[64][36], Khi[64][36], Klo[64][36];
  const int t = threadIdx.x;
  const int row = t >> 2, ci = (t & 3) * 8;
  const int w = t >> 6, lane = t & 63;
  const int quad = lane >> 4, l16 = lane & 15;
  const int mw = (w & 1) * 32, nw = (w >> 1) * 32;
  // stage Q tile once
  {
    const size_t qbase = ((size_t)bh * 512 + i0 + row) * 32 + ci;
    *(int4*)&Qhi[row][ci]     = *(const int4*)&QhiG[qbase];
    *(int4*)&Qhi[row][ci + 4] = *(const int4*)&QhiG[qbase + 4];
    *(int4*)&Qlo[row][ci]     = *(const int4*)&QloG[qbase];
    *(int4*)&Qlo[row][ci + 4] = *(const int4*)&QloG[qbase + 4];
  }
  // hoist per-row qn
  float qni_r[2][4], rq_r[2][4];
#pragma unroll
  for (int i = 0; i < 2; ++i)
#pragma unroll
    for (int r = 0; r < 4; ++r) {
      const int grow = i0 + mw + i * 16 + quad * 4 + r;
      qni_r[i][r] = qn[(size_t)bh * 512 + grow];
      rq_r[i][r]  = 1.0f - qni_r[i][r];
    }
  float rs_acc[2][4];
#pragma unroll
  for (int i = 0; i < 2; ++i)
#pragma unroll
    for (int r = 0; r < 4; ++r) rs_acc[i][r] = 0.0f;

  for (int j0i = 0; j0i < 4; ++j0i) {
    const int j0 = jh * 256 + j0i * 64;
    const size_t kbase = ((size_t)bh * 512 + j0 + row) * 32 + ci;
    const int4 kh0 = *(const int4*)&KhiG[kbase];
    const int4 kh1 = *(const int4*)&KhiG[kbase + 4];
    const int4 kl0 = *(const int4*)&KloG[kbase];
    const int4 kl1 = *(const int4*)&KloG[kbase + 4];
    __syncthreads();   // prior iteration's K reads complete
    *(int4*)&Khi[row][ci]     = kh0;
    *(int4*)&Khi[row][ci + 4] = kh1;
    *(int4*)&Klo[row][ci]     = kl0;
    *(int4*)&Klo[row][ci + 4] = kl1;
    __syncthreads();   // K (and on iter 0, Q) visible
    floatx4 acc[2][2];
#pragma unroll
    for (int i = 0; i < 2; ++i)
#pragma unroll
      for (int j = 0; j < 2; ++j) acc[i][j] = (floatx4){0.f, 0.f, 0.f, 0.f};
#pragma unroll
    for (int kk = 0; kk < 64; kk += 32) {
      short8 ah[2], al[2], bhv[2], blv[2];
#pragma unroll
      for (int i = 0; i < 2; ++i) {
        ah[i]  = *(const short8*)&((const short*)Qhi[mw + i * 16 + l16])[kk + quad * 8];
        al[i]  = *(const short8*)&((const short*)Qlo[mw + i * 16 + l16])[kk + quad * 8];
        bhv[i] = *(const short8*)&((const short*)Khi[nw + i * 16 + l16])[kk + quad * 8];
        blv[i] = *(const short8*)&((const short*)Klo[nw + i * 16 + l16])[kk + quad * 8];
      }
#pragma unroll
      for (int i = 0; i < 2; ++i)
#pragma unroll
        for (int j = 0; j < 2; ++j) {
          acc[i][j] = __builtin_amdgcn_mfma_f32_16x16x32_bf16(ah[i], bhv[j], acc[i][j], 0, 0, 0);
          acc[i][j] = __builtin_amdgcn_mfma_f32_16x16x32_bf16(ah[i], blv[j], acc[i][j], 0, 0, 0);
          acc[i][j] = __builtin_amdgcn_mfma_f32_16x16x32_bf16(al[i], bhv[j], acc[i][j], 0, 0, 0);
        }
    }
#pragma unroll
    for (int i = 0; i < 2; ++i)
#pragma unroll
      for (int r = 0; r < 4; ++r) {
        const int grow = i0 + mw + i * 16 + quad * 4 + r;
        const float qni = qni_r[i][r];
        const float rq  = rq_r[i][r];
#pragma unroll
        for (int j = 0; j < 2; ++j) {
          const int gcol = j0 + nw + j * 16 + l16;
          const float knj = kn[(size_t)bh * 512 + gcol];
          const float num = fmaxf(qni + knj - 2.0f * acc[i][j][r], 0.0f);
          const float den = fmaxf(rq * (1.0f - knj), EPS);
          const float wv = fmaf(2.0f * num, __builtin_amdgcn_rcpf(den), EPS);
          const float s_ = 1.0f + wv + sqrtf(wv * (wv + 2.0f));
          const float rr = __builtin_amdgcn_rcpf(s_);
          rs_acc[i][r] += rr;
          attn[((size_t)bh * 512 + grow) * 512 + gcol] = rr;
        }
      }
  }
#pragma unroll
  for (int i = 0; i < 2; ++i)
#pragma unroll
    for (int r = 0; r < 4; ++r) {
      float v = rs_acc[i][r];
      v += __shfl_xor(v, 1, 64); v += __shfl_xor(v, 2, 64);
      v += __shfl_xor(v, 4, 64); v += __shfl_xor(v, 8, 64);
      if (l16 == 0)
        atomicAdd(&rowsum[(size_t)bh * 512 + i0 + mw + i * 16 + quad * 4 + r], v);
    }
}

// ---------- K6 v13: mobius scan (verified best) ----------
__global__ __launch_bounds__(256) void k_scan(const float* __restrict__ V,
                                              const float* __restrict__ vn,
                                              const float* __restrict__ rw,
                                              const float* __restrict__ rowsum,
                                              float* __restrict__ att) {
  __shared__ __align__(16) float v_lds[64 * 64];
  __shared__ __align__(16) float swyn_lds[64 * 66];
  const int blk = blockIdx.x;
  const int bh = blk >> 4;
  const int i0 = (blk & 15) * 32;
  const int t = threadIdx.x;
  const int lane = t & 63, w = t >> 6;
  const int row_blk = w * 8 + (lane >> 3);
  const int sub = lane & 7;
  const int d0 = sub * 8;
  const float* Vb = V + (size_t)bh * 512 * 64;
  const float* vnb = vn + (size_t)bh * 512;
  const float* arow = rw + ((size_t)bh * 512 + i0 + row_blk) * 512;
  const float inv_s = __builtin_amdgcn_rcpf(rowsum[(size_t)bh * 512 + i0 + row_blk]);

  float2v wsv[4];
#pragma unroll
  for (int k = 0; k < 4; ++k) wsv[k] = (float2v){0.f, 0.f};
  float xn = 0.0f;

  for (int jc = 0; jc < 512; jc += 64) {
#pragma unroll
    for (int it = 0; it < 4; ++it) {
      const int idx4 = it * 256 + t;
      *(float4*)&v_lds[idx4 * 4] = *(const float4*)&Vb[(size_t)jc * 64 + idx4 * 4];
    }
    const float4 a0 = *(const float4*)&arow[jc + sub * 8];
    const float4 a1 = *(const float4*)&arow[jc + sub * 8 + 4];
    const float4 n0 = *(const float4*)&vnb[jc + sub * 8];
    const float4 n1 = *(const float4*)&vnb[jc + sub * 8 + 4];
    const float wq[8] = {a0.x, a0.y, a0.z, a0.w, a1.x, a1.y, a1.z, a1.w};
    const float nq[8] = {n0.x, n0.y, n0.z, n0.w, n1.x, n1.y, n1.z, n1.w};
#pragma unroll
    for (int e = 0; e < 8; ++e) {
      const float wgt = wq[e] * inv_s;
      float2 p; p.x = wgt; p.y = (wgt * wgt) * nq[e];
      *(float2*)&swyn_lds[(sub * 8 + e) * 66 + row_blk * 2] = p;
    }
    __syncthreads();

    float4 pv0 = *(const float4*)&v_lds[d0];
    float4 pv1 = *(const float4*)&v_lds[d0 + 4];
    float2 psy = *(const float2*)&swyn_lds[row_blk * 2];
#pragma unroll
    for (int j = 0; j < 64; ++j) {
      const float4 v0 = pv0;
      const float4 v1 = pv1;
      const float2 sy2 = psy;
      if (j < 63) {
        pv0 = *(const float4*)&v_lds[(j + 1) * 64 + d0];
        pv1 = *(const float4*)&v_lds[(j + 1) * 64 + d0 + 4];
        psy = *(const float2*)&swyn_lds[(j + 1) * 66 + row_blk * 2];
      }
      const float2v vv0 = {v0.x, v0.y}, vv1 = {v0.z, v0.w};
      const float2v vv2 = {v1.x, v1.y}, vv3 = {v1.z, v1.w};
      const float sw = sy2.x, yn = sy2.y;
      const float xnyn1 = fmaf(xn, yn, 1.0f + EPS);
      const float sxy   = xn + yn;
      const float ynp1  = 1.0f + yn;
      const float Cfsw  = (1.0f - xn) * sw;
      float2v da = wsv[0] * vv0;
      da = fma2(wsv[1], vv1, da);
      float2v db = wsv[2] * vv2;
      db = fma2(wsv[3], vv3, db);
      const float2v sv = da + db;
      float d = sv.x + sv.y;
      d += qperm<QP_XOR1>(d);
      d += qperm<QP_XOR2>(d);
      d += qperm<QP_HALFMIR>(d);
      const float xy  = sw * d;
      const float den = fmaf(2.0f, xy, xnyn1);
      const float s2  = fmaf(2.0f, xy, sxy);
      const float Af  = fmaf(2.0f, xy, ynp1);
      const float id  = __builtin_amdgcn_rcpf(den);
      const float dn  = den - EPS;
      const float am  = Af * id;
      const float cm  = Cfsw * id;
      xn = (s2 * id) * (dn * id);
      const float2v amv = {am, am};
      const float2v cmv = {cm, cm};
      wsv[0] = fma2(amv, wsv[0], cmv * vv0);
      wsv[1] = fma2(amv, wsv[1], cmv * vv1);
      wsv[2] = fma2(amv, wsv[2], cmv * vv2);
      wsv[3] = fma2(amv, wsv[3], cmv * vv3);
    }
    __syncthreads();
  }
  const int b = bh >> 3, h = bh & 7;
  float* o = att + (((size_t)b * 512 + i0 + row_blk) * 512 + h * 64 + d0);
  float4 s0; s0.x = wsv[0].x; s0.y = wsv[0].y; s0.z = wsv[1].x; s0.w = wsv[1].y;
  float4 s1; s1.x = wsv[2].x; s1.y = wsv[2].y; s1.z = wsv[3].x; s1.w = wsv[3].y;
  *(float4*)&o[0] = s0;
  *(float4*)&o[4] = s1;
}

extern "C" void kernel_launch(void* const* d_in, const int* in_sizes, int n_in,
                              void* d_out, int out_size, void* d_ws, size_t ws_size,
                              hipStream_t stream) {
  const float* query = (const float*)d_in[0];
  const float* key_  = (const float*)d_in[1];
  const float* value = (const float*)d_in[2];
  const float* Wq = (const float*)d_in[3];
  const float* bq = (const float*)d_in[4];
  const float* Wk = (const float*)d_in[5];
  const float* bk = (const float*)d_in[6];
  const float* Wv = (const float*)d_in[7];
  const float* bv = (const float*)d_in[8];
  const float* Wo = (const float*)d_in[9];
  const float* bo = (const float*)d_in[10];
  float* ws = (float*)d_ws;
  const size_t M = 1u << 20;            // 1M floats
  // packed Q/K in [0, 2M)
  int* qhi = (int*)ws;
  int* qlo = (int*)ws + 524288;
  int* khi = (int*)ws + 1048576;
  int* klo = (int*)ws + 1572864;
  float* Vb     = ws + 2 * M;           // [32,512,64]
  float* qn     = ws + 3 * M;           // [32,512]
  float* kn     = qn + 16384;
  float* vn     = kn + 16384;
  float* rowsum = vn + 16384;           // ends at 3M + 65536
  // W splits
  int* wsl = (int*)(ws + 3 * M + 65536);
  int* whq = wsl,          * wlq = wsl + 131072;
  int* whk = wsl + 262144, * wlk = wsl + 393216;
  int* whv = wsl + 524288, * wlv = wsl + 655360;
  float* rw     = ws + 4 * M;           // [32,512,512]
  float* t3     = ws + 12 * M;          // 3x [2048,512]
  int* who  = (int*)(ws + 12 * M);      // Wo split reuses t3 region (dead after k_post)
  int* wlo_ = (int*)(ws + 12 * M) + 131072;
  float* att    = ws + 15 * M;          // [2048,512]
  float* to_    = ws + 16 * M;          // [2048,512]

  k_splitW<<<dim3(512, 3), 256, 0, stream>>>(Wq, Wk, Wv, whq, wlq, whk, wlk, whv, wlv);
  k_gemm_mfma<<<dim3(32, 8, 3), 256, 0, stream>>>(query, key_, value,
                                                  whq, wlq, whk, wlk, whv, wlv, t3);
  k_post<<<dim3(2048, 3), 256, 0, stream>>>(t3, bq, bk, bv, nullptr, nullptr, Vb,
                                            qn, kn, vn, rowsum, qhi, qlo, khi, klo, 0);
  k_splitW<<<dim3(512, 1), 256, 0, stream>>>(Wo, Wo, Wo, who, wlo_, who, wlo_, who, wlo_);
  k_logits<<<dim3(8, 2, 32), 256, 0, stream>>>(qhi, qlo, khi, klo, qn, kn, rw, rowsum);
  k_scan<<<512, 256, 0, stream>>>(Vb, vn, rw, rowsum, att);
  k_gemm_mfma<<<dim3(32, 8, 1), 256, 0, stream>>>(att, att, att,
                                                  who, wlo_, who, wlo_, who, wlo_, to_);
  k_post<<<dim3(2048, 1), 256, 0, stream>>>(to_, bo, bo, bo, (float*)d_out,
                                            nullptr, nullptr, nullptr, nullptr, nullptr,
                                            nullptr, nullptr, nullptr, nullptr, nullptr, 1);
}

// Round 11
// 228.825 us; speedup vs baseline: 1.0333x; 1.0135x over previous
//
#include <hip/hip_runtime.h>
#include <math.h>

#define EPS  1e-5f
#define EPS2 1e-10f
#define MAXN (1.0f - EPS)

using short8  = __attribute__((ext_vector_type(8))) short;
using floatx4 = __attribute__((ext_vector_type(4))) float;
using float2v = __attribute__((ext_vector_type(2))) float;

template <int CTRL>
static __device__ __forceinline__ float qperm(float x) {
  return __int_as_float(__builtin_amdgcn_update_dpp(
      __float_as_int(x), __float_as_int(x), CTRL, 0xF, 0xF, false));
}
#define QP_XOR1    0xB1
#define QP_XOR2    0x4E
#define QP_HALFMIR 0x141

#if __has_builtin(__builtin_elementwise_fma)
static __device__ __forceinline__ float2v fma2(float2v a, float2v b, float2v c) {
  return __builtin_elementwise_fma(a, b, c);
}
#else
static __device__ __forceinline__ float2v fma2(float2v a, float2v b, float2v c) {
  float2v r; r.x = fmaf(a.x, b.x, c.x); r.y = fmaf(a.y, b.y, c.y); return r;
}
#endif

static __device__ __forceinline__ int pack_hi2(float a, float b) {
  return (int)((__float_as_uint(a) >> 16) | (__float_as_uint(b) & 0xFFFF0000u));
}
static __device__ __forceinline__ float hi_of(float a) {
  return __uint_as_float(__float_as_uint(a) & 0xFFFF0000u);
}

static __device__ __forceinline__ float logmap_f(float ss) {
  const float r = sqrtf(fmaxf(ss, EPS2));
  float at;
  if (r >= MAXN) {
    at = 0.5f * logf((r * (2.0f - EPS) + EPS) / (EPS * (1.0f + r)));
  } else {
    at = 0.5f * logf((1.0f + r) / (1.0f - r));
  }
  return (1.0f + EPS) * at / r;
}

// ---------- K1: pre-split W matrices to packed bf16 hi/lo ----------
__global__ __launch_bounds__(256) void k_splitW(
    const float* __restrict__ W0, const float* __restrict__ W1, const float* __restrict__ W2,
    int* __restrict__ h0, int* __restrict__ l0,
    int* __restrict__ h1, int* __restrict__ l1,
    int* __restrict__ h2, int* __restrict__ l2) {
  const int row = blockIdx.x, z = blockIdx.y, t = threadIdx.x;
  const float* W = (z == 0) ? W0 : ((z == 1) ? W1 : W2);
  int* H = (z == 0) ? h0 : ((z == 1) ? h1 : h2);
  int* L = (z == 0) ? l0 : ((z == 1) ? l1 : l2);
  const float2 w = *(const float2*)&W[(size_t)row * 512 + 2 * t];
  H[(size_t)row * 256 + t] = pack_hi2(w.x, w.y);
  L[(size_t)row * 256 + t] = pack_hi2(w.x - hi_of(w.x), w.y - hi_of(w.y));
}

// ---------- K2: C = f[row]*(A @ W^T), W pre-split ----------
__global__ __launch_bounds__(256) void k_gemm_mfma(
    const float* __restrict__ A0, const float* __restrict__ A1, const float* __restrict__ A2,
    const int* __restrict__ Wh0, const int* __restrict__ Wl0,
    const int* __restrict__ Wh1, const int* __restrict__ Wl1,
    const int* __restrict__ Wh2, const int* __restrict__ Wl2,
    float* __restrict__ Cbase) {
  const int z = blockIdx.z;
  const float* A = (z == 0) ? A0 : ((z == 1) ? A1 : A2);
  const int* Wh = (z == 0) ? Wh0 : ((z == 1) ? Wh1 : Wh2);
  const int* Wl = (z == 0) ? Wl0 : ((z == 1) ? Wl1 : Wl2);
  float* C = Cbase + (size_t)z * (2048 * 512);
  __shared__ int Ahi[64][36], Alo[64][36], Whi[64][36], Wlo[64][36];
  __shared__ float f_lds[64];
  const int t = threadIdx.x;
  const int n0 = blockIdx.x * 64;
  const int m0 = blockIdx.y * 64;
  const int row = t >> 2, c0 = (t & 3) * 16, ci = (t & 3) * 8;
  const int w = t >> 6, lane = t & 63;
  const int quad = lane >> 4, l16 = lane & 15;
  const int mw = (w & 1) * 32, nw = (w >> 1) * 32;
  floatx4 acc[2][2];
#pragma unroll
  for (int i = 0; i < 2; ++i)
#pragma unroll
    for (int j = 0; j < 2; ++j) acc[i][j] = (floatx4){0.f, 0.f, 0.f, 0.f};
  float ssq = 0.0f;

  for (int k0 = 0; k0 < 512; k0 += 64) {
    float4 av[4];
#pragma unroll
    for (int i = 0; i < 4; ++i)
      av[i] = *(const float4*)&A[(size_t)(n0 + row) * 512 + k0 + c0 + 4 * i];
    const size_t wbase = (size_t)(m0 + row) * 256 + (k0 >> 1) + ci;
    const int4 wh0 = *(const int4*)&Wh[wbase];
    const int4 wh1 = *(const int4*)&Wh[wbase + 4];
    const int4 wl0 = *(const int4*)&Wl[wbase];
    const int4 wl1 = *(const int4*)&Wl[wbase + 4];
    int pAh[8], pAl[8];
#pragma unroll
    for (int i = 0; i < 4; ++i) {
      ssq = fmaf(av[i].x, av[i].x, ssq); ssq = fmaf(av[i].y, av[i].y, ssq);
      ssq = fmaf(av[i].z, av[i].z, ssq); ssq = fmaf(av[i].w, av[i].w, ssq);
      pAh[2 * i]     = pack_hi2(av[i].x, av[i].y);
      pAh[2 * i + 1] = pack_hi2(av[i].z, av[i].w);
      pAl[2 * i]     = pack_hi2(av[i].x - hi_of(av[i].x), av[i].y - hi_of(av[i].y));
      pAl[2 * i + 1] = pack_hi2(av[i].z - hi_of(av[i].z), av[i].w - hi_of(av[i].w));
    }
    __syncthreads();
    *(int4*)&Ahi[row][ci]     = *(int4*)&pAh[0];
    *(int4*)&Ahi[row][ci + 4] = *(int4*)&pAh[4];
    *(int4*)&Alo[row][ci]     = *(int4*)&pAl[0];
    *(int4*)&Alo[row][ci + 4] = *(int4*)&pAl[4];
    *(int4*)&Whi[row][ci]     = wh0;
    *(int4*)&Whi[row][ci + 4] = wh1;
    *(int4*)&Wlo[row][ci]     = wl0;
    *(int4*)&Wlo[row][ci + 4] = wl1;
    __syncthreads();
#pragma unroll
    for (int kk = 0; kk < 64; kk += 32) {
      short8 ah[2], al[2], bh[2], bl[2];
#pragma unroll
      for (int i = 0; i < 2; ++i) {
        ah[i] = *(const short8*)&((const short*)Ahi[mw + i * 16 + l16])[kk + quad * 8];
        al[i] = *(const short8*)&((const short*)Alo[mw + i * 16 + l16])[kk + quad * 8];
        bh[i] = *(const short8*)&((const short*)Whi[nw + i * 16 + l16])[kk + quad * 8];
        bl[i] = *(const short8*)&((const short*)Wlo[nw + i * 16 + l16])[kk + quad * 8];
      }
#pragma unroll
      for (int i = 0; i < 2; ++i)
#pragma unroll
        for (int j = 0; j < 2; ++j) {
          acc[i][j] = __builtin_amdgcn_mfma_f32_16x16x32_bf16(ah[i], bh[j], acc[i][j], 0, 0, 0);
          acc[i][j] = __builtin_amdgcn_mfma_f32_16x16x32_bf16(ah[i], bl[j], acc[i][j], 0, 0, 0);
          acc[i][j] = __builtin_amdgcn_mfma_f32_16x16x32_bf16(al[i], bh[j], acc[i][j], 0, 0, 0);
        }
    }
  }
  ssq += qperm<QP_XOR1>(ssq);
  ssq += qperm<QP_XOR2>(ssq);
  if ((t & 3) == 0) f_lds[row] = logmap_f(ssq);
  __syncthreads();
#pragma unroll
  for (int i = 0; i < 2; ++i) {
    const int lrow_base = mw + i * 16 + quad * 4;
#pragma unroll
    for (int r = 0; r < 4; ++r) {
      const float fv = f_lds[lrow_base + r];
#pragma unroll
      for (int j = 0; j < 2; ++j)
        C[(size_t)(n0 + lrow_base + r) * 512 + m0 + nw + j * 16 + l16] = fv * acc[i][j][r];
    }
  }
}

// ---------- K3: expmap0 + mobius-add bias; Q/K emitted PRE-PACKED bf16 hi/lo ----------
__global__ __launch_bounds__(256) void k_post(const float* __restrict__ tin,
                                              const float* __restrict__ b0,
                                              const float* __restrict__ b1,
                                              const float* __restrict__ b2,
                                              float* __restrict__ o0, float* __restrict__ o1,
                                              float* __restrict__ o2,
                                              float* __restrict__ nrm0, float* __restrict__ nrm1,
                                              float* __restrict__ nrm2,
                                              float* __restrict__ rowsum_init,
                                              int* __restrict__ qhi, int* __restrict__ qlo,
                                              int* __restrict__ khi, int* __restrict__ klo,
                                              int final_mode) {
  const int nrow = blockIdx.x, z = blockIdx.y, t = threadIdx.x;
  const float* tv = tin + ((size_t)z * 2048 + nrow) * 512;
  const float* bias = (z == 0) ? b0 : ((z == 1) ? b1 : b2);
  const int e0 = 2 * t;
  const float2 tp = *(const float2*)&tv[e0];
  const float2 bp = *(const float2*)&bias[e0];
  float p_tt = tp.x * tp.x + tp.y * tp.y;
  float p_tb = tp.x * bp.x + tp.y * bp.y;
  float p_bb = bp.x * bp.x + bp.y * bp.y;
#pragma unroll
  for (int m = 32; m; m >>= 1) {
    p_tt += __shfl_xor(p_tt, m, 64);
    p_tb += __shfl_xor(p_tb, m, 64);
    p_bb += __shfl_xor(p_bb, m, 64);
  }
  __shared__ float red[4][3];
  const int lane = t & 63, w = t >> 6;
  if (lane == 0) { red[w][0] = p_tt; red[w][1] = p_tb; red[w][2] = p_bb; }
  __syncthreads();
  const float s_tt = red[0][0] + red[1][0] + red[2][0] + red[3][0];
  const float s_tb = red[0][1] + red[1][1] + red[2][1] + red[3][1];
  const float s_bb = red[0][2] + red[1][2] + red[2][2] + red[3][2];
  const float tn = sqrtf(fmaxf(s_tt, EPS2));
  const float th = tanhf(tn / (1.0f + EPS));
  const float g = th / tn;
  const float rnorm = th * (sqrtf(s_tt) / tn);
  const float sr = (rnorm >= MAXN) ? (MAXN / (rnorm + EPS)) : 1.0f;
  const float gr = g * sr;
  const float rn = (rnorm * sr) * (rnorm * sr);
  const float bnorm = sqrtf(fmaxf(s_bb, EPS2));
  const float sb = (bnorm >= MAXN) ? (MAXN / (bnorm + EPS)) : 1.0f;
  const float xy = gr * sb * s_tb;
  const float yn = (sb * sb) * s_bb;
  const float Af = 1.0f + 2.0f * xy + yn;
  const float Cf = 1.0f - rn;
  const float den = 1.0f + 2.0f * xy + rn * yn + EPS;
  const float id = 1.0f / den;
  const float on_raw = (Af * Af * rn + 2.0f * Af * Cf * xy + Cf * Cf * yn) * (id * id);
  const float no = sqrtf(fmaxf(on_raw, EPS2));
  const float so = (no >= MAXN) ? (MAXN / (no + EPS)) : 1.0f;
  const float ms = id * so;
  const float ca = gr * Af * ms;
  const float cb = sb * Cf * ms;
  const float v0 = ca * tp.x + cb * bp.x;
  const float v1 = ca * tp.y + cb * bp.y;
  if (final_mode) {
    float2 o; o.x = v0; o.y = v1;
    *(float2*)&o0[(size_t)nrow * 512 + e0] = o;
    return;
  }
  float hp = v0 * v0 + v1 * v1;
#pragma unroll
  for (int m = 16; m; m >>= 1) hp += __shfl_xor(hp, m, 64);
  const float hnr = sqrtf(fmaxf(hp, EPS2));
  float sh = 1.0f;
  if (z != 2) sh = (hnr >= MAXN) ? (MAXN / (hnr + EPS)) : 1.0f;
  float* nz = (z == 0) ? nrm0 : ((z == 1) ? nrm1 : nrm2);
  const int b = nrow >> 9, s = nrow & 511, h = e0 >> 6, d = e0 & 63;
  const float ox = v0 * sh, oy = v1 * sh;
  if (z == 2) {
    float2 o; o.x = ox; o.y = oy;
    *(float2*)&o2[(((size_t)(b * 8 + h) * 512 + s) * 64 + d)] = o;
  } else {
    int* Hp = (z == 0) ? qhi : khi;
    int* Lp = (z == 0) ? qlo : klo;
    const size_t pidx = ((size_t)(b * 8 + h) * 512 + s) * 32 + (d >> 1);
    Hp[pidx] = pack_hi2(ox, oy);
    Lp[pidx] = pack_hi2(ox - hi_of(ox), oy - hi_of(oy));
  }
  if ((t & 31) == 0) nz[(size_t)(b * 8 + h) * 512 + s] = hp * sh * sh;
  if (z == 0 && t < 8) rowsum_init[((size_t)(nrow >> 9) * 8 + t) * 512 + (nrow & 511)] = 0.0f;
}

// ---------- K4 v2: QK^T from pre-packed Q/K; Q staged ONCE, 4 K-tiles per block ----------
__global__ __launch_bounds__(256) void k_logits(const int* __restrict__ QhiG,
                                                const int* __restrict__ QloG,
                                                const int* __restrict__ KhiG,
                                                const int* __restrict__ KloG,
                                                const float* __restrict__ qn,
                                                const float* __restrict__ kn,
                                                float* __restrict__ attn,
                                                float* __restrict__ rowsum) {
  const int bh = blockIdx.z;
  const int i0 = blockIdx.x * 64;
  const int jh = blockIdx.y;                 // j-half: K tiles jh*256 + {0,64,128,192}
  __shared__ int Qhi[64][36], Qlo[64][36], Khi[64][36], Klo[64][36];
  const int t = threadIdx.x;
  const int row = t >> 2, ci = (t & 3) * 8;
  const int w = t >> 6, lane = t & 63;
  const int quad = lane >> 4, l16 = lane & 15;
  const int mw = (w & 1) * 32, nw = (w >> 1) * 32;
  // stage Q tile once
  {
    const size_t qbase = ((size_t)bh * 512 + i0 + row) * 32 + ci;
    *(int4*)&Qhi[row][ci]     = *(const int4*)&QhiG[qbase];
    *(int4*)&Qhi[row][ci + 4] = *(const int4*)&QhiG[qbase + 4];
    *(int4*)&Qlo[row][ci]     = *(const int4*)&QloG[qbase];
    *(int4*)&Qlo[row][ci + 4] = *(const int4*)&QloG[qbase + 4];
  }
  // hoist per-row qn
  float qni_r[2][4], rq_r[2][4];
#pragma unroll
  for (int i = 0; i < 2; ++i)
#pragma unroll
    for (int r = 0; r < 4; ++r) {
      const int grow = i0 + mw + i * 16 + quad * 4 + r;
      qni_r[i][r] = qn[(size_t)bh * 512 + grow];
      rq_r[i][r]  = 1.0f - qni_r[i][r];
    }
  float rs_acc[2][4];
#pragma unroll
  for (int i = 0; i < 2; ++i)
#pragma unroll
    for (int r = 0; r < 4; ++r) rs_acc[i][r] = 0.0f;

  for (int j0i = 0; j0i < 4; ++j0i) {
    const int j0 = jh * 256 + j0i * 64;
    const size_t kbase = ((size_t)bh * 512 + j0 + row) * 32 + ci;
    const int4 kh0 = *(const int4*)&KhiG[kbase];
    const int4 kh1 = *(const int4*)&KhiG[kbase + 4];
    const int4 kl0 = *(const int4*)&KloG[kbase];
    const int4 kl1 = *(const int4*)&KloG[kbase + 4];
    __syncthreads();   // prior iteration's K reads complete
    *(int4*)&Khi[row][ci]     = kh0;
    *(int4*)&Khi[row][ci + 4] = kh1;
    *(int4*)&Klo[row][ci]     = kl0;
    *(int4*)&Klo[row][ci + 4] = kl1;
    __syncthreads();   // K (and on iter 0, Q) visible
    floatx4 acc[2][2];
#pragma unroll
    for (int i = 0; i < 2; ++i)
#pragma unroll
      for (int j = 0; j < 2; ++j) acc[i][j] = (floatx4){0.f, 0.f, 0.f, 0.f};
#pragma unroll
    for (int kk = 0; kk < 64; kk += 32) {
      short8 ah[2], al[2], bhv[2], blv[2];
#pragma unroll
      for (int i = 0; i < 2; ++i) {
        ah[i]  = *(const short8*)&((const short*)Qhi[mw + i * 16 + l16])[kk + quad * 8];
        al[i]  = *(const short8*)&((const short*)Qlo[mw + i * 16 + l16])[kk + quad * 8];
        bhv[i] = *(const short8*)&((const short*)Khi[nw + i * 16 + l16])[kk + quad * 8];
        blv[i] = *(const short8*)&((const short*)Klo[nw + i * 16 + l16])[kk + quad * 8];
      }
#pragma unroll
      for (int i = 0; i < 2; ++i)
#pragma unroll
        for (int j = 0; j < 2; ++j) {
          acc[i][j] = __builtin_amdgcn_mfma_f32_16x16x32_bf16(ah[i], bhv[j], acc[i][j], 0, 0, 0);
          acc[i][j] = __builtin_amdgcn_mfma_f32_16x16x32_bf16(ah[i], blv[j], acc[i][j], 0, 0, 0);
          acc[i][j] = __builtin_amdgcn_mfma_f32_16x16x32_bf16(al[i], bhv[j], acc[i][j], 0, 0, 0);
        }
    }
#pragma unroll
    for (int i = 0; i < 2; ++i)
#pragma unroll
      for (int r = 0; r < 4; ++r) {
        const int grow = i0 + mw + i * 16 + quad * 4 + r;
        const float qni = qni_r[i][r];
        const float rq  = rq_r[i][r];
#pragma unroll
        for (int j = 0; j < 2; ++j) {
          const int gcol = j0 + nw + j * 16 + l16;
          const float knj = kn[(size_t)bh * 512 + gcol];
          const float num = fmaxf(qni + knj - 2.0f * acc[i][j][r], 0.0f);
          const float den = fmaxf(rq * (1.0f - knj), EPS);
          const float wv = fmaf(2.0f * num, __builtin_amdgcn_rcpf(den), EPS);
          const float s_ = 1.0f + wv + sqrtf(wv * (wv + 2.0f));
          const float rr = __builtin_amdgcn_rcpf(s_);
          rs_acc[i][r] += rr;
          attn[((size_t)bh * 512 + grow) * 512 + gcol] = rr;
        }
      }
  }
#pragma unroll
  for (int i = 0; i < 2; ++i)
#pragma unroll
    for (int r = 0; r < 4; ++r) {
      float v = rs_acc[i][r];
      v += __shfl_xor(v, 1, 64); v += __shfl_xor(v, 2, 64);
      v += __shfl_xor(v, 4, 64); v += __shfl_xor(v, 8, 64);
      if (l16 == 0)
        atomicAdd(&rowsum[(size_t)bh * 512 + i0 + mw + i * 16 + quad * 4 + r], v);
    }
}

// ---------- K6 v13: mobius scan (verified best) ----------
__global__ __launch_bounds__(256) void k_scan(const float* __restrict__ V,
                                              const float* __restrict__ vn,
                                              const float* __restrict__ rw,
                                              const float* __restrict__ rowsum,
                                              float* __restrict__ att) {
  __shared__ __align__(16) float v_lds[64 * 64];
  __shared__ __align__(16) float swyn_lds[64 * 66];
  const int blk = blockIdx.x;
  const int bh = blk >> 4;
  const int i0 = (blk & 15) * 32;
  const int t = threadIdx.x;
  const int lane = t & 63, w = t >> 6;
  const int row_blk = w * 8 + (lane >> 3);
  const int sub = lane & 7;
  const int d0 = sub * 8;
  const float* Vb = V + (size_t)bh * 512 * 64;
  const float* vnb = vn + (size_t)bh * 512;
  const float* arow = rw + ((size_t)bh * 512 + i0 + row_blk) * 512;
  const float inv_s = __builtin_amdgcn_rcpf(rowsum[(size_t)bh * 512 + i0 + row_blk]);

  float2v wsv[4];
#pragma unroll
  for (int k = 0; k < 4; ++k) wsv[k] = (float2v){0.f, 0.f};
  float xn = 0.0f;

  for (int jc = 0; jc < 512; jc += 64) {
#pragma unroll
    for (int it = 0; it < 4; ++it) {
      const int idx4 = it * 256 + t;
      *(float4*)&v_lds[idx4 * 4] = *(const float4*)&Vb[(size_t)jc * 64 + idx4 * 4];
    }
    const float4 a0 = *(const float4*)&arow[jc + sub * 8];
    const float4 a1 = *(const float4*)&arow[jc + sub * 8 + 4];
    const float4 n0 = *(const float4*)&vnb[jc + sub * 8];
    const float4 n1 = *(const float4*)&vnb[jc + sub * 8 + 4];
    const float wq[8] = {a0.x, a0.y, a0.z, a0.w, a1.x, a1.y, a1.z, a1.w};
    const float nq[8] = {n0.x, n0.y, n0.z, n0.w, n1.x, n1.y, n1.z, n1.w};
#pragma unroll
    for (int e = 0; e < 8; ++e) {
      const float wgt = wq[e] * inv_s;
      float2 p; p.x = wgt; p.y = (wgt * wgt) * nq[e];
      *(float2*)&swyn_lds[(sub * 8 + e) * 66 + row_blk * 2] = p;
    }
    __syncthreads();

    float4 pv0 = *(const float4*)&v_lds[d0];
    float4 pv1 = *(const float4*)&v_lds[d0 + 4];
    float2 psy = *(const float2*)&swyn_lds[row_blk * 2];
#pragma unroll
    for (int j = 0; j < 64; ++j) {
      const float4 v0 = pv0;
      const float4 v1 = pv1;
      const float2 sy2 = psy;
      if (j < 63) {
        pv0 = *(const float4*)&v_lds[(j + 1) * 64 + d0];
        pv1 = *(const float4*)&v_lds[(j + 1) * 64 + d0 + 4];
        psy = *(const float2*)&swyn_lds[(j + 1) * 66 + row_blk * 2];
      }
      const float2v vv0 = {v0.x, v0.y}, vv1 = {v0.z, v0.w};
      const float2v vv2 = {v1.x, v1.y}, vv3 = {v1.z, v1.w};
      const float sw = sy2.x, yn = sy2.y;
      const float xnyn1 = fmaf(xn, yn, 1.0f + EPS);
      const float sxy   = xn + yn;
      const float ynp1  = 1.0f + yn;
      const float Cfsw  = (1.0f - xn) * sw;
      float2v da = wsv[0] * vv0;
      da = fma2(wsv[1], vv1, da);
      float2v db = wsv[2] * vv2;
      db = fma2(wsv[3], vv3, db);
      const float2v sv = da + db;
      float d = sv.x + sv.y;
      d += qperm<QP_XOR1>(d);
      d += qperm<QP_XOR2>(d);
      d += qperm<QP_HALFMIR>(d);
      const float xy  = sw * d;
      const float den = fmaf(2.0f, xy, xnyn1);
      const float s2  = fmaf(2.0f, xy, sxy);
      const float Af  = fmaf(2.0f, xy, ynp1);
      const float id  = __builtin_amdgcn_rcpf(den);
      const float dn  = den - EPS;
      const float am  = Af * id;
      const float cm  = Cfsw * id;
      xn = (s2 * id) * (dn * id);
      const float2v amv = {am, am};
      const float2v cmv = {cm, cm};
      wsv[0] = fma2(amv, wsv[0], cmv * vv0);
      wsv[1] = fma2(amv, wsv[1], cmv * vv1);
      wsv[2] = fma2(amv, wsv[2], cmv * vv2);
      wsv[3] = fma2(amv, wsv[3], cmv * vv3);
    }
    __syncthreads();
  }
  const int b = bh >> 3, h = bh & 7;
  float* o = att + (((size_t)b * 512 + i0 + row_blk) * 512 + h * 64 + d0);
  float4 s0; s0.x = wsv[0].x; s0.y = wsv[0].y; s0.z = wsv[1].x; s0.w = wsv[1].y;
  float4 s1; s1.x = wsv[2].x; s1.y = wsv[2].y; s1.z = wsv[3].x; s1.w = wsv[3].y;
  *(float4*)&o[0] = s0;
  *(float4*)&o[4] = s1;
}

extern "C" void kernel_launch(void* const* d_in, const int* in_sizes, int n_in,
                              void* d_out, int out_size, void* d_ws, size_t ws_size,
                              hipStream_t stream) {
  const float* query = (const float*)d_in[0];
  const float* key_  = (const float*)d_in[1];
  const float* value = (const float*)d_in[2];
  const float* Wq = (const float*)d_in[3];
  const float* bq = (const float*)d_in[4];
  const float* Wk = (const float*)d_in[5];
  const float* bk = (const float*)d_in[6];
  const float* Wv = (const float*)d_in[7];
  const float* bv = (const float*)d_in[8];
  const float* Wo = (const float*)d_in[9];
  const float* bo = (const float*)d_in[10];
  float* ws = (float*)d_ws;
  const size_t M = 1u << 20;            // 1M floats
  // packed Q/K in [0, 2M)
  int* qhi = (int*)ws;
  int* qlo = (int*)ws + 524288;
  int* khi = (int*)ws + 1048576;
  int* klo = (int*)ws + 1572864;
  float* Vb     = ws + 2 * M;           // [32,512,64]
  float* qn     = ws + 3 * M;           // [32,512]
  float* kn     = qn + 16384;
  float* vn     = kn + 16384;
  float* rowsum = vn + 16384;           // ends at 3M + 65536
  // W splits
  int* wsl = (int*)(ws + 3 * M + 65536);
  int* whq = wsl,          * wlq = wsl + 131072;
  int* whk = wsl + 262144, * wlk = wsl + 393216;
  int* whv = wsl + 524288, * wlv = wsl + 655360;
  float* rw     = ws + 4 * M;           // [32,512,512]
  float* t3     = ws + 12 * M;          // 3x [2048,512]
  int* who  = (int*)(ws + 12 * M);      // Wo split reuses t3 region (dead after k_post)
  int* wlo_ = (int*)(ws + 12 * M) + 131072;
  float* att    = ws + 15 * M;          // [2048,512]
  float* to_    = ws + 16 * M;          // [2048,512]

  k_splitW<<<dim3(512, 3), 256, 0, stream>>>(Wq, Wk, Wv, whq, wlq, whk, wlk, whv, wlv);
  k_gemm_mfma<<<dim3(32, 8, 3), 256, 0, stream>>>(query, key_, value,
                                                  whq, wlq, whk, wlk, whv, wlv, t3);
  k_post<<<dim3(2048, 3), 256, 0, stream>>>(t3, bq, bk, bv, nullptr, nullptr, Vb,
                                            qn, kn, vn, rowsum, qhi, qlo, khi, klo, 0);
  k_splitW<<<dim3(512, 1), 256, 0, stream>>>(Wo, Wo, Wo, who, wlo_, who, wlo_, who, wlo_);
  k_logits<<<dim3(8, 2, 32), 256, 0, stream>>>(qhi, qlo, khi, klo, qn, kn, rw, rowsum);
  k_scan<<<512, 256, 0, stream>>>(Vb, vn, rw, rowsum, att);
  k_gemm_mfma<<<dim3(32, 8, 1), 256, 0, stream>>>(att, att, att,
                                                  who, wlo_, who, wlo_, who, wlo_, to_);
  k_post<<<dim3(2048, 1), 256, 0, stream>>>(to_, bo, bo, bo, (float*)d_out,
                                            nullptr, nullptr, nullptr, nullptr, nullptr,
                                            nullptr, nullptr, nullptr, nullptr, nullptr, 1);
}